// Round 1
// baseline (369.794 us; speedup 1.0000x reference)
//
#include <hip/hip_runtime.h>

#define EMBED 64
#define BATCH 4096

__global__ __launch_bounds__(256) void fm_kernel(
    const float* __restrict__ emb,
    const float* __restrict__ vals,
    const int*   __restrict__ bids,
    const int*   __restrict__ fids,
    float*       __restrict__ out,
    int nnz)
{
    const int wave_in_block = threadIdx.x >> 6;
    const int lane          = threadIdx.x & 63;
    const int row           = blockIdx.x * 4 + wave_in_block;
    if (row >= BATCH) return;

    // lower_bound(row): first idx with bids[idx] >= row  (wave-uniform search)
    int lo = 0, hi = nnz;
    while (lo < hi) {
        int mid = (lo + hi) >> 1;
        if (bids[mid] < row) lo = mid + 1; else hi = mid;
    }
    const int start = lo;
    hi = nnz;
    while (lo < hi) {
        int mid = (lo + hi) >> 1;
        if (bids[mid] < row + 1) lo = mid + 1; else hi = mid;
    }
    const int end = lo;

    float s = 0.f, sq = 0.f;
    int i = start;
    for (; i + 4 <= end; i += 4) {
        float v0 = vals[i + 0], v1 = vals[i + 1], v2 = vals[i + 2], v3 = vals[i + 3];
        int   f0 = fids[i + 0], f1 = fids[i + 1], f2 = fids[i + 2], f3 = fids[i + 3];
        float e0 = emb[(size_t)f0 * EMBED + lane];
        float e1 = emb[(size_t)f1 * EMBED + lane];
        float e2 = emb[(size_t)f2 * EMBED + lane];
        float e3 = emb[(size_t)f3 * EMBED + lane];
        float a0 = v0 * e0, a1 = v1 * e1, a2 = v2 * e2, a3 = v3 * e3;
        s  += (a0 + a1) + (a2 + a3);
        sq += (a0 * a0 + a1 * a1) + (a2 * a2 + a3 * a3);
    }
    for (; i < end; ++i) {
        float v = vals[i];
        int   f = fids[i];
        float e = emb[(size_t)f * EMBED + lane];
        float a = v * e;
        s  += a;
        sq += a * a;
    }

    out[(size_t)row * EMBED + lane] = 0.5f * (s * s - sq);
}

extern "C" void kernel_launch(void* const* d_in, const int* in_sizes, int n_in,
                              void* d_out, int out_size, void* d_ws, size_t ws_size,
                              hipStream_t stream) {
    const float* emb  = (const float*)d_in[0];
    const float* vals = (const float*)d_in[1];
    const int*   bids = (const int*)d_in[2];
    const int*   fids = (const int*)d_in[3];
    float*       out  = (float*)d_out;
    const int nnz = in_sizes[1];

    const int rows_per_block = 4;                       // 256 threads = 4 waves
    const int blocks = (BATCH + rows_per_block - 1) / rows_per_block;
    fm_kernel<<<dim3(blocks), dim3(256), 0, stream>>>(emb, vals, bids, fids, out, nnz);
}